// Round 1
// baseline (79.426 us; speedup 1.0000x reference)
//
#include <hip/hip_runtime.h>
#include <hip/hip_bf16.h>

#define Q 4096
#define L 8192

// ---------------------------------------------------------------------------
// Kernel 1: score[l] = dot(context[l], query), one block per row.
// ---------------------------------------------------------------------------
__global__ __launch_bounds__(256) void score_kernel(
    const float* __restrict__ ctx, const float* __restrict__ q,
    float* __restrict__ score)
{
    const int l = blockIdx.x;
    const float4* __restrict__ row = (const float4*)(ctx + (size_t)l * Q);
    const float4* __restrict__ qv  = (const float4*)q;

    float acc = 0.f;
    #pragma unroll
    for (int i = threadIdx.x; i < Q / 4; i += 256) {
        float4 a = row[i];
        float4 b = qv[i];
        acc = fmaf(a.x, b.x, acc);
        acc = fmaf(a.y, b.y, acc);
        acc = fmaf(a.z, b.z, acc);
        acc = fmaf(a.w, b.w, acc);
    }

    // wave (64) reduce, then 4-wave LDS reduce
    #pragma unroll
    for (int off = 32; off > 0; off >>= 1) acc += __shfl_down(acc, off, 64);

    __shared__ float red[4];
    const int lane = threadIdx.x & 63;
    const int wid  = threadIdx.x >> 6;
    if (lane == 0) red[wid] = acc;
    __syncthreads();
    if (threadIdx.x == 0)
        score[l] = red[0] + red[1] + red[2] + red[3];
}

// ---------------------------------------------------------------------------
// Kernel 2: attention = softmax(score) over all L elements. Single block.
// ---------------------------------------------------------------------------
__global__ __launch_bounds__(1024) void softmax_kernel(
    const float* __restrict__ score, float* __restrict__ att)
{
    __shared__ float redm[16];
    __shared__ float reds[16];
    const int tid  = threadIdx.x;
    const int lane = tid & 63;
    const int wid  = tid >> 6;

    // --- global max ---
    float m = -3.4e38f;
    for (int i = tid; i < L; i += 1024) m = fmaxf(m, score[i]);
    #pragma unroll
    for (int off = 32; off > 0; off >>= 1) m = fmaxf(m, __shfl_down(m, off, 64));
    if (lane == 0) redm[wid] = m;
    __syncthreads();
    float mfull = redm[0];
    #pragma unroll
    for (int w = 1; w < 16; ++w) mfull = fmaxf(mfull, redm[w]);

    // --- sum of exp ---
    float s = 0.f;
    for (int i = tid; i < L; i += 1024) s += expf(score[i] - mfull);
    #pragma unroll
    for (int off = 32; off > 0; off >>= 1) s += __shfl_down(s, off, 64);
    if (lane == 0) reds[wid] = s;
    __syncthreads();
    float stot = 0.f;
    #pragma unroll
    for (int w = 0; w < 16; ++w) stot += reds[w];
    const float inv = 1.0f / stot;

    // --- write normalized attention ---
    for (int i = tid; i < L; i += 1024) att[i] = expf(score[i] - mfull) * inv;
}

// ---------------------------------------------------------------------------
// Kernel 3: partial[cl][q] = sum over 256-row chunk of att[l]*ctx[l][q].
// grid = (4 column-chunks of 1024 cols, 32 row-chunks of 256 rows)
// ---------------------------------------------------------------------------
__global__ __launch_bounds__(256) void wsum_partial_kernel(
    const float* __restrict__ ctx, const float* __restrict__ att,
    float* __restrict__ partial)
{
    __shared__ float a_s[256];
    const int cq = blockIdx.x;   // 0..3
    const int cl = blockIdx.y;   // 0..31

    a_s[threadIdx.x] = att[cl * 256 + threadIdx.x];
    __syncthreads();

    const int col4 = cq * 256 + threadIdx.x;       // float4 index within a row
    const float4* __restrict__ base = (const float4*)ctx;

    float4 acc = make_float4(0.f, 0.f, 0.f, 0.f);
    #pragma unroll 4
    for (int r = 0; r < 256; ++r) {
        const float a = a_s[r];
        float4 v = base[(size_t)(cl * 256 + r) * (Q / 4) + col4];
        acc.x = fmaf(a, v.x, acc.x);
        acc.y = fmaf(a, v.y, acc.y);
        acc.z = fmaf(a, v.z, acc.z);
        acc.w = fmaf(a, v.w, acc.w);
    }
    ((float4*)partial)[(size_t)cl * (Q / 4) + col4] = acc;
}

// ---------------------------------------------------------------------------
// Kernel 4: s_t[q] = sum over 32 partials. grid = 4 blocks x 256 threads.
// ---------------------------------------------------------------------------
__global__ __launch_bounds__(256) void wsum_reduce_kernel(
    const float* __restrict__ partial, float* __restrict__ s_t)
{
    const int col4 = blockIdx.x * 256 + threadIdx.x;
    const float4* __restrict__ p = (const float4*)partial;
    float4 acc = make_float4(0.f, 0.f, 0.f, 0.f);
    #pragma unroll
    for (int cl = 0; cl < 32; ++cl) {
        float4 v = p[(size_t)cl * (Q / 4) + col4];
        acc.x += v.x; acc.y += v.y; acc.z += v.z; acc.w += v.w;
    }
    ((float4*)s_t)[col4] = acc;
}

// ---------------------------------------------------------------------------
// Kernel 5: out[i] = K_w[i, 0:Q] . query + K_w[i, Q:2Q] . s_t
// One block per output row.
// ---------------------------------------------------------------------------
__global__ __launch_bounds__(256) void out_mv_kernel(
    const float* __restrict__ Kw, const float* __restrict__ q,
    const float* __restrict__ s_t, float* __restrict__ out)
{
    const int i = blockIdx.x;
    const float4* __restrict__ row = (const float4*)(Kw + (size_t)i * (2 * Q));
    const float4* __restrict__ qv  = (const float4*)q;
    const float4* __restrict__ sv  = (const float4*)s_t;

    float acc = 0.f;
    #pragma unroll
    for (int j = threadIdx.x; j < Q / 4; j += 256) {
        float4 a = row[j];
        float4 b = qv[j];
        acc = fmaf(a.x, b.x, acc);
        acc = fmaf(a.y, b.y, acc);
        acc = fmaf(a.z, b.z, acc);
        acc = fmaf(a.w, b.w, acc);
    }
    #pragma unroll
    for (int j = threadIdx.x; j < Q / 4; j += 256) {
        float4 a = row[Q / 4 + j];
        float4 b = sv[j];
        acc = fmaf(a.x, b.x, acc);
        acc = fmaf(a.y, b.y, acc);
        acc = fmaf(a.z, b.z, acc);
        acc = fmaf(a.w, b.w, acc);
    }

    #pragma unroll
    for (int off = 32; off > 0; off >>= 1) acc += __shfl_down(acc, off, 64);

    __shared__ float red[4];
    const int lane = threadIdx.x & 63;
    const int wid  = threadIdx.x >> 6;
    if (lane == 0) red[wid] = acc;
    __syncthreads();
    if (threadIdx.x == 0)
        out[i] = red[0] + red[1] + red[2] + red[3];
}

// ---------------------------------------------------------------------------
extern "C" void kernel_launch(void* const* d_in, const int* in_sizes, int n_in,
                              void* d_out, int out_size, void* d_ws, size_t ws_size,
                              hipStream_t stream)
{
    const float* query = (const float*)d_in[0];   // [Q]
    const float* ctx   = (const float*)d_in[1];   // [L, Q]
    const float* Kw    = (const float*)d_in[2];   // [Q, 2Q]
    float* out = (float*)d_out;                   // [Q]

    // workspace layout (floats)
    float* ws      = (float*)d_ws;
    float* score   = ws;                 // L       = 8192
    float* att     = ws + L;             // L       = 8192
    float* s_t     = ws + 2 * L;         // Q       = 4096
    float* partial = ws + 2 * L + Q;     // 32 * Q  = 131072

    score_kernel<<<L, 256, 0, stream>>>(ctx, query, score);
    softmax_kernel<<<1, 1024, 0, stream>>>(score, att);
    wsum_partial_kernel<<<dim3(4, 32), 256, 0, stream>>>(ctx, att, partial);
    wsum_reduce_kernel<<<4, 256, 0, stream>>>(partial, s_t);
    out_mv_kernel<<<Q, 256, 0, stream>>>(Kw, query, s_t, out);
}